// Round 9
// baseline (711.176 us; speedup 1.0000x reference)
//
#include <hip/hip_runtime.h>

typedef __bf16 bf16_t;
typedef __attribute__((ext_vector_type(8))) __bf16 bf16x8;
typedef __attribute__((ext_vector_type(4))) float f32x4;
typedef unsigned short u16;
typedef unsigned int u32;
typedef unsigned long long u64;

#define TC 128      // steps per chunk
#define NCH 8
#define XGHALF 16777216  // u16 elements per xg half (33.5 MB)
#define LDA 264   // 256 + 8 bf16 pad
#define LOG2E 1.44269504f

// LDS-visibility-only barrier: leaves global prefetch loads (vmcnt) in flight.
#define LDS_BARRIER() asm volatile("s_waitcnt lgkmcnt(0)\n\ts_barrier" ::: "memory")

#if __has_builtin(__builtin_amdgcn_exp2f)
#define EXP2F __builtin_amdgcn_exp2f
#else
static __device__ __forceinline__ float EXP2F(float x) {
  float r;
  asm volatile("v_exp_f32 %0, %1\n\ts_nop 1" : "=v"(r) : "v"(x));
  return r;
}
#endif

// ws layout (bytes), total ~72.9 MB:
//   xg   @ 0         : 2 halves x 64*128*2048*2 = 67,108,864
//   embb @ 67108864  : 10000*256*2 = 5,120,000
//   wkt  @ 72228864  : 512*256*2   =   262,144
//   hst  @ 72491008  : 64*4*128*4  =   131,072  (f32 h carry)
//   cst  @ 72622080  : 64*4*128*4  =   131,072  (f32 c carry)
//   wrt  @ 72753152  : 512*128*2   =   131,072  (bf16 Wr frags, scan layout)
//
// xg step-block layout (u16, 2048 per (g,t)), GATE-CONTIGUOUS:
//   pos(column n = j*128+u, row r) = u*16 + r*4 + j
//   Scan thread (w,quad,l16): unit u=16w+l16, row quad -> ONE b64 load at
//   u*16 + quad*4 yields gates j=0..3 adjacent.
//
// Launch schedule: cs=-2 bake-only (embb/wkt/wrt); cs=-1: xgemm chunk 0;
// cs=0..6: scan(cs) || xgemm(cs+1); cs=7: scan only. Producer always ran in
// a PREVIOUS launch -> kernel-boundary visibility, no flags.

static __device__ __forceinline__ u16 bf16bits(float v) {
  return __builtin_bit_cast(u16, (bf16_t)v);
}
static __device__ __forceinline__ float bf16f(u16 v) {
  return __builtin_bit_cast(float, (u32)v << 16);
}

__global__ __launch_bounds__(512) void k_fused(
    const int* __restrict__ x, const float* __restrict__ emb,
    u16* __restrict__ embb, const float* __restrict__ Wk,
    u16* __restrict__ wkt, const float* __restrict__ Wr,
    u16* __restrict__ wrt, const float* __restrict__ bias,
    const float* __restrict__ Wd, const float* __restrict__ bd,
    u16* __restrict__ xg, float* __restrict__ hstf, float* __restrict__ cstf,
    float* __restrict__ out, int cs) {
  const int tid = threadIdx.x;
  const int w = tid >> 6, lane = tid & 63;
  const int l16 = lane & 15, quad = lane >> 4;

  if (cs == -2) {
    // ======== bake-only dispatch (521 wgs): embb, wkt, wrt ========
    const int bid = blockIdx.x;
    if (bid >= 9) {
      // embb: bf16 embedding table (512 wgs)
      for (int i = (bid - 9) * 512 + tid; i < 2560000; i += 262144)
        embb[i] = bf16bits(emb[i]);
    } else if (bid == 8) {
      // wrt: Wr frags in scan thread layout, gate-scaled (1 wg)
      const int u = 16 * w + l16;
#pragma unroll
      for (int j = 0; j < 4; ++j) {
        const float sj = (j == 2) ? 1.0f : -LOG2E;
#pragma unroll
        for (int kt = 0; kt < 4; ++kt)
#pragma unroll
          for (int jj = 0; jj < 8; ++jj)
            wrt[tid * 128 + (j * 4 + kt) * 8 + jj] =
                bf16bits(Wr[(kt * 32 + quad * 8 + jj) * 512 + u + 128 * j] * sj);
      }
    } else {
      // wkt: WkT[n][k] = Wk[k][n] (8 wgs)
      for (int i = bid * 512 + tid; i < 131072; i += 4096) {
        int k = i & 255, n = i >> 8;
        wkt[i] = bf16bits(Wk[k * 512 + n]);
      }
    }
    return;
  }

  if (blockIdx.x >= 64) {
    // ============ xgemm worker: one 64-row tile of chunk cb = cs+1 ========
    const int cb = cs + 1;
    if (cb >= NCH) return;
    const int tau = blockIdx.x - 64;  // 0..511
    const int gg = tau >> 5, tb = tau & 31;
    u16* xgc = xg + (size_t)(cb & 1) * XGHALF;
    __shared__ u16 Al[64 * LDA];
    __shared__ float biasl[512];

    bf16x8 bfr[4][8];
#pragma unroll
    for (int nt = 0; nt < 4; ++nt) {
      const u16* bp = wkt + (64 * w + 16 * nt + l16) * 256 + quad * 8;
#pragma unroll
      for (int kt = 0; kt < 8; ++kt)
        bfr[nt][kt] = *(const bf16x8*)(bp + kt * 32);
    }

#pragma unroll
    for (int p = 0; p < 4; ++p) {
      int f = p * 512 + tid;
      int lr = f >> 5, ch = f & 31;
      int xi = (16 * gg + (lr & 15)) * 1024 + cb * TC + tb * 4 + (lr >> 4);
      int idx = x[xi];
      *(uint4*)&Al[lr * LDA + ch * 8] = *(const uint4*)&embb[idx * 256 + ch * 8];
    }
    biasl[tid] = bias[tid];
    __syncthreads();

    f32x4 acc[4][4];
#pragma unroll
    for (int mt = 0; mt < 4; ++mt)
#pragma unroll
      for (int nt = 0; nt < 4; ++nt) acc[mt][nt] = f32x4{0.f, 0.f, 0.f, 0.f};
#pragma unroll
    for (int kt = 0; kt < 8; ++kt) {
      bf16x8 a[4];
#pragma unroll
      for (int mt = 0; mt < 4; ++mt)
        a[mt] = *(const bf16x8*)&Al[(mt * 16 + l16) * LDA + kt * 32 + quad * 8];
#pragma unroll
      for (int nt = 0; nt < 4; ++nt)
#pragma unroll
        for (int mt = 0; mt < 4; ++mt)
          acc[mt][nt] = __builtin_amdgcn_mfma_f32_16x16x32_bf16(
              a[mt], bfr[nt][kt], acc[mt][nt], 0, 0, 0);
    }

    // Scatter-store in gate-contiguous layout: pos(n=j*128+u, r) = u*16+r*4+j.
    // 64 ushort stores/thread; producer has ~50us slack under the scan, the
    // consumer's 4 gate loads collapse to ONE b64 load on its serial chain.
    const float gsc = ((w >> 1) == 2) ? 1.0f : -LOG2E;
    const size_t gtbase = ((size_t)(4 * gg + quad) * TC + tb * 4) * 2048;
#pragma unroll
    for (int nt = 0; nt < 4; ++nt) {
      float bv = biasl[64 * w + 16 * nt + l16];
      int n = 64 * w + 16 * nt + l16;
      int j = n >> 7, uu = n & 127;
      u16* base = xgc + gtbase + uu * 16 + j;
#pragma unroll
      for (int mt = 0; mt < 4; ++mt)
#pragma unroll
        for (int r = 0; r < 4; ++r)
          base[mt * 2048 + r * 4] = bf16bits((acc[mt][nt][r] + bv) * gsc);
    }
  } else {
    // ================= scan chunk cs (TC=128) ==============
    if (cs < 0) return;
    const int g = blockIdx.x;
    const int u = 16 * w + l16;
    __shared__ __align__(16) u16 hbuf[2][4 * 144];

    // Priority boost: protects the latency chain against xgemm co-residents
    // during the overlap window at the head of each dispatch.
    __builtin_amdgcn_s_setprio(1);

    // wf preload from pre-baked wrt: 16 coalesced b128 loads
    bf16x8 wf[4][4];
    {
      const u16* wp = wrt + tid * 128;
#pragma unroll
      for (int j = 0; j < 4; ++j)
#pragma unroll
        for (int kt = 0; kt < 4; ++kt)
          wf[j][kt] = *(const bf16x8*)(wp + (j * 4 + kt) * 8);
    }

    float c1 = 0.f, h1 = 0.f;
    if (cs != 0) {
      c1 = cstf[(g * 4 + quad) * 128 + u];
      h1 = hstf[(g * 4 + quad) * 128 + u];
    }
    hbuf[0][quad * 144 + u] = bf16bits(h1);

    // Broadcast A-reads (conflict-free): all lanes of a 4-lane group read the
    // same row (l16>>2); garbage rows land only in C rows never consumed.
    const u16* rd0 = &hbuf[0][(l16 >> 2) * 144 + quad * 8];
    const u16* rd1 = &hbuf[1][(l16 >> 2) * 144 + quad * 8];
    u16* wr0 = &hbuf[0][quad * 144 + u];
    u16* wr1 = &hbuf[1][quad * 144 + u];

    // xg: ONE b64 per halfstep (gates contiguous), prefetch depth 4.
    const u16* xb = xg + (size_t)(cs & 1) * XGHALF + (size_t)g * TC * 2048 +
                    u * 16 + quad * 4;
    u64 xq0 = *(const u64*)(xb);
    u64 xq1 = *(const u64*)(xb + 2048);
    u64 xq2 = *(const u64*)(xb + 2 * 2048);
    u64 xq3 = *(const u64*)(xb + 3 * 2048);
    const u16* xp = xb + 4 * 2048;

    __syncthreads();

    auto halfstep = [&](const u16* rd, u16* wr, u64& xv) {
      // ds_reads: a0 first (feeds accA chain), a2 second (feeds accB chain)
      bf16x8 a0 = *(const bf16x8*)(rd);
      bf16x8 a2 = *(const bf16x8*)(rd + 2 * 32);
      bf16x8 a1 = *(const bf16x8*)(rd + 1 * 32);
      bf16x8 a3 = *(const bf16x8*)(rd + 3 * 32);
      // unpack this step's 4 gate pre-activations (loaded 4 halfsteps ago)
      u32 lo = (u32)xv, hi = (u32)(xv >> 32);
      float x0 = __builtin_bit_cast(float, lo << 16);
      float x1 = __builtin_bit_cast(float, lo & 0xffff0000u);
      float x2 = __builtin_bit_cast(float, hi << 16);
      float x3 = __builtin_bit_cast(float, hi & 0xffff0000u);
      // re-prefetch 4 steps ahead (stays in flight across barriers;
      // chunk-edge overshoot lands in valid ws and is discarded)
      xv = *(const u64*)xp;
      xp += 2048;
      // Two independent 2-deep MFMA chains per gate (was one 4-deep chain):
      // saves ~2 MFMA result-latencies on the serial path; merge is 1 f32 add
      // since only C reg 0 is consumed.
      const f32x4 c0 = {0.f, 0.f, 0.f, 0.f};
      f32x4 accA[4], accB[4];
#pragma unroll
      for (int j = 0; j < 4; ++j)
        accA[j] =
            __builtin_amdgcn_mfma_f32_16x16x32_bf16(a0, wf[j][0], c0, 0, 0, 0);
#pragma unroll
      for (int j = 0; j < 4; ++j)
        accB[j] =
            __builtin_amdgcn_mfma_f32_16x16x32_bf16(a2, wf[j][2], c0, 0, 0, 0);
#pragma unroll
      for (int j = 0; j < 4; ++j)
        accA[j] = __builtin_amdgcn_mfma_f32_16x16x32_bf16(a1, wf[j][1],
                                                          accA[j], 0, 0, 0);
#pragma unroll
      for (int j = 0; j < 4; ++j)
        accB[j] = __builtin_amdgcn_mfma_f32_16x16x32_bf16(a3, wf[j][3],
                                                          accB[j], 0, 0, 0);
      float zi = accA[0][0] + accB[0][0] + x0;
      float zf = accA[1][0] + accB[1][0] + x1;
      float zc = accA[2][0] + accB[2][0] + x2;
      float zo = accA[3][0] + accB[3][0] + x3;
      float ig = __builtin_amdgcn_rcpf(1.f + EXP2F(zi));
      float fg = __builtin_amdgcn_rcpf(1.f + EXP2F(zf));
      float og = __builtin_amdgcn_rcpf(1.f + EXP2F(zo));
      float gg = fmaxf(zc, 0.f);
      c1 = fg * c1 + ig * gg;
      h1 = og * fmaxf(c1, 0.f);
      *wr = bf16bits(h1);
      LDS_BARRIER();
    };

    for (int t4 = 0; t4 < TC; t4 += 4) {
      halfstep(rd0, wr1, xq0);  // t even: read buf0, write buf1
      halfstep(rd1, wr0, xq1);  // t odd:  read buf1, write buf0
      halfstep(rd0, wr1, xq2);
      halfstep(rd1, wr0, xq3);
    }

    if (cs != NCH - 1) {
      cstf[(g * 4 + quad) * 128 + u] = c1;
      hstf[(g * 4 + quad) * 128 + u] = h1;
    } else if (tid < 8) {
      // final h in hbuf[0] (t=127 wrote buf 0; barrier passed)
      int p = tid >> 1, jo = tid & 1;
      float o = bd[jo];
      for (int k = 0; k < 128; ++k)
        o += bf16f(hbuf[0][p * 144 + k]) * Wd[k * 2 + jo];
      out[(g * 4 + p) * 2 + jo] = o;
    }
  }
}

extern "C" void kernel_launch(void* const* d_in, const int* in_sizes, int n_in,
                              void* d_out, int out_size, void* d_ws, size_t ws_size,
                              hipStream_t stream) {
  const int* x = (const int*)d_in[0];
  const float* emb = (const float*)d_in[1];
  const float* Wk = (const float*)d_in[2];
  const float* Wr = (const float*)d_in[3];
  const float* bias = (const float*)d_in[4];
  const float* Wd = (const float*)d_in[5];
  const float* bd = (const float*)d_in[6];
  float* out = (float*)d_out;
  char* ws = (char*)d_ws;
  u16* xg = (u16*)(ws);
  u16* embb = (u16*)(ws + 67108864);
  u16* wkt = (u16*)(ws + 72228864);
  float* hst = (float*)(ws + 72491008);
  float* cst = (float*)(ws + 72622080);
  u16* wrt = (u16*)(ws + 72753152);

  // cs=-2: bake embb/wkt/wrt (tiny); cs=-1: xgemm(0); cs=0..6: scan(cs) ||
  // xgemm(cs+1); cs=7: scan(7) only.
  k_fused<<<521, 512, 0, stream>>>(x, emb, embb, Wk, wkt, Wr, wrt, bias, Wd,
                                   bd, xg, hst, cst, out, -2);
  for (int cs = -1; cs < NCH; ++cs) {
    int nwg = (cs + 1 < NCH) ? 576 : 64;
    k_fused<<<nwg, 512, 0, stream>>>(x, emb, embb, Wk, wkt, Wr, wrt, bias,
                                     Wd, bd, xg, hst, cst, out, cs);
  }
}

// Round 12
// 554.787 us; speedup vs baseline: 1.2819x; 1.2819x over previous
//
#include <hip/hip_runtime.h>

typedef __bf16 bf16_t;
typedef __attribute__((ext_vector_type(8))) __bf16 bf16x8;
typedef __attribute__((ext_vector_type(4))) float f32x4;
typedef unsigned short u16;
typedef unsigned int u32;
typedef unsigned long long u64;

#define TC 128      // steps per chunk
#define NCH 8
#define XGHALF 16777216  // u16 elements per xg half (33.5 MB)
#define LDA 264   // 256 + 8 bf16 pad
#define LOG2E 1.44269504f

// LDS-visibility-only barrier: leaves global prefetch loads (vmcnt) in flight.
#define LDS_BARRIER() asm volatile("s_waitcnt lgkmcnt(0)\n\ts_barrier" ::: "memory")

#if __has_builtin(__builtin_amdgcn_exp2f)
#define EXP2F __builtin_amdgcn_exp2f
#else
static __device__ __forceinline__ float EXP2F(float x) {
  float r;
  asm volatile("v_exp_f32 %0, %1\n\ts_nop 1" : "=v"(r) : "v"(x));
  return r;
}
#endif

// ws layout (bytes), total ~72.9 MB:
//   xg   @ 0         : 2 halves x 64*128*2048*2 = 67,108,864
//   embb @ 67108864  : 10000*256*2 = 5,120,000
//   wkt  @ 72228864  : 512*256*2   =   262,144
//   hst  @ 72491008  : 64*4*128*4  =   131,072  (f32 h carry)
//   cst  @ 72622080  : 64*4*128*4  =   131,072  (f32 c carry)
//   wrt  @ 72753152  : 512*128*2   =   131,072  (bf16 Wr frags, scan layout)
//
// xg step-block layout (u16, 2048 per (g,t)), GATE-CONTIGUOUS:
//   pos(unit u, batch-row r, gate j) = u*16 + r*4 + j   (col n = j*128+u)
//   Scan thread (w,quad,l16): unit u=16w+l16, row quad -> ONE b64 load at
//   u*16 + quad*4 yields gates j=0..3 adjacent.
//   Producer (R9 fix): wave->column remap n = 16w + l16 + 128*nt makes each
//   thread own ALL 4 gates of unit u=16w+l16 -> its 16 acc values are the 32
//   CONTIGUOUS bytes [u*16, u*16+16) -> 8x16B coalesced stores (512B/quad),
//   no scatter, no partial-line RMW (R9: +10MB FETCH, +40MB WRITE, 81us).
//
// Launch schedule: cs=-2 bake-only (embb/wkt/wrt); cs=-1: xgemm chunk 0;
// cs=0..6: scan(cs) || xgemm(cs+1); cs=7: scan only. Producer always ran in
// a PREVIOUS launch -> kernel-boundary visibility, no flags.

static __device__ __forceinline__ u16 bf16bits(float v) {
  return __builtin_bit_cast(u16, (bf16_t)v);
}
static __device__ __forceinline__ float bf16f(u16 v) {
  return __builtin_bit_cast(float, (u32)v << 16);
}

__global__ __launch_bounds__(512) void k_fused(
    const int* __restrict__ x, const float* __restrict__ emb,
    u16* __restrict__ embb, const float* __restrict__ Wk,
    u16* __restrict__ wkt, const float* __restrict__ Wr,
    u16* __restrict__ wrt, const float* __restrict__ bias,
    const float* __restrict__ Wd, const float* __restrict__ bd,
    u16* __restrict__ xg, float* __restrict__ hstf, float* __restrict__ cstf,
    float* __restrict__ out, int cs) {
  const int tid = threadIdx.x;
  const int w = tid >> 6, lane = tid & 63;
  const int l16 = lane & 15, quad = lane >> 4;

  if (cs == -2) {
    // ======== bake-only dispatch (521 wgs): embb, wkt, wrt ========
    const int bid = blockIdx.x;
    if (bid >= 9) {
      // embb: bf16 embedding table (512 wgs)
      for (int i = (bid - 9) * 512 + tid; i < 2560000; i += 262144)
        embb[i] = bf16bits(emb[i]);
    } else if (bid == 8) {
      // wrt: Wr frags in scan thread layout, gate-scaled (1 wg)
      const int u = 16 * w + l16;
#pragma unroll
      for (int j = 0; j < 4; ++j) {
        const float sj = (j == 2) ? 1.0f : -LOG2E;
#pragma unroll
        for (int kt = 0; kt < 4; ++kt)
#pragma unroll
          for (int jj = 0; jj < 8; ++jj)
            wrt[tid * 128 + (j * 4 + kt) * 8 + jj] =
                bf16bits(Wr[(kt * 32 + quad * 8 + jj) * 512 + u + 128 * j] * sj);
      }
    } else {
      // wkt: WkT[n][k] = Wk[k][n] (8 wgs)
      for (int i = bid * 512 + tid; i < 131072; i += 4096) {
        int k = i & 255, n = i >> 8;
        wkt[i] = bf16bits(Wk[k * 512 + n]);
      }
    }
    return;
  }

  if (blockIdx.x >= 64) {
    // ============ xgemm worker: one 64-row tile of chunk cb = cs+1 ========
    const int cb = cs + 1;
    if (cb >= NCH) return;
    const int tau = blockIdx.x - 64;  // 0..511
    const int gg = tau >> 5, tb = tau & 31;
    u16* xgc = xg + (size_t)(cb & 1) * XGHALF;
    __shared__ u16 Al[64 * LDA];
    __shared__ float biasl[512];
    const int u = 16 * w + l16;  // unit owned by this thread (0..127)

    // B frags: wave->gate-slice remap. Col n = u + 128*nt (nt == gate j).
    bf16x8 bfr[4][8];
#pragma unroll
    for (int nt = 0; nt < 4; ++nt) {
      const u16* bp = wkt + (u + 128 * nt) * 256 + quad * 8;
#pragma unroll
      for (int kt = 0; kt < 8; ++kt)
        bfr[nt][kt] = *(const bf16x8*)(bp + kt * 32);
    }

#pragma unroll
    for (int p = 0; p < 4; ++p) {
      int f = p * 512 + tid;
      int lr = f >> 5, ch = f & 31;
      int xi = (16 * gg + (lr & 15)) * 1024 + cb * TC + tb * 4 + (lr >> 4);
      int idx = x[xi];
      *(uint4*)&Al[lr * LDA + ch * 8] = *(const uint4*)&embb[idx * 256 + ch * 8];
    }
    biasl[tid] = bias[tid];
    __syncthreads();

    f32x4 acc[4][4];
#pragma unroll
    for (int mt = 0; mt < 4; ++mt)
#pragma unroll
      for (int nt = 0; nt < 4; ++nt) acc[mt][nt] = f32x4{0.f, 0.f, 0.f, 0.f};
#pragma unroll
    for (int kt = 0; kt < 8; ++kt) {
      bf16x8 a[4];
#pragma unroll
      for (int mt = 0; mt < 4; ++mt)
        a[mt] = *(const bf16x8*)&Al[(mt * 16 + l16) * LDA + kt * 32 + quad * 8];
#pragma unroll
      for (int nt = 0; nt < 4; ++nt)
#pragma unroll
        for (int mt = 0; mt < 4; ++mt)
          acc[mt][nt] = __builtin_amdgcn_mfma_f32_16x16x32_bf16(
              a[mt], bfr[nt][kt], acc[mt][nt], 0, 0, 0);
    }

    // Epilogue: thread's 16 acc values (gate j, row r) are the contiguous
    // 32B [u*16, u*16+16) of the gate-contiguous layout. 8x16B coalesced
    // stores/thread; 16 lanes/quad -> 512B contiguous per quad per mt.
    float bvj[4];
#pragma unroll
    for (int j = 0; j < 4; ++j) bvj[j] = biasl[u + 128 * j];
    const size_t rowbase = (size_t)(4 * gg + quad) * TC + tb * 4;
#pragma unroll
    for (int mt = 0; mt < 4; ++mt) {
      u16 tmp[16];
#pragma unroll
      for (int j = 0; j < 4; ++j) {
        const float sj = (j == 2) ? 1.0f : -LOG2E;
#pragma unroll
        for (int r = 0; r < 4; ++r)
          tmp[r * 4 + j] = bf16bits((acc[mt][j][r] + bvj[j]) * sj);
      }
      u16* dst = xgc + (rowbase + mt) * 2048 + u * 16;
      *(uint4*)(dst) = *(const uint4*)(tmp);
      *(uint4*)(dst + 8) = *(const uint4*)(tmp + 8);
    }
  } else {
    // ================= scan chunk cs (TC=128) ==============
    if (cs < 0) return;
    const int g = blockIdx.x;
    const int u = 16 * w + l16;
    __shared__ __align__(16) u16 hbuf[2][4 * 144];

    // Priority boost: protects the latency chain against xgemm co-residents
    // during the overlap window at the head of each dispatch.
    __builtin_amdgcn_s_setprio(1);

    // wf preload from pre-baked wrt: 16 coalesced b128 loads
    bf16x8 wf[4][4];
    {
      const u16* wp = wrt + tid * 128;
#pragma unroll
      for (int j = 0; j < 4; ++j)
#pragma unroll
        for (int kt = 0; kt < 4; ++kt)
          wf[j][kt] = *(const bf16x8*)(wp + (j * 4 + kt) * 8);
    }

    float c1 = 0.f, h1 = 0.f;
    if (cs != 0) {
      c1 = cstf[(g * 4 + quad) * 128 + u];
      h1 = hstf[(g * 4 + quad) * 128 + u];
    }
    hbuf[0][quad * 144 + u] = bf16bits(h1);

    // Broadcast A-reads (conflict-free): all lanes of a 4-lane group read the
    // same row (l16>>2); garbage rows land only in C rows never consumed.
    const u16* rd0 = &hbuf[0][(l16 >> 2) * 144 + quad * 8];
    const u16* rd1 = &hbuf[1][(l16 >> 2) * 144 + quad * 8];
    u16* wr0 = &hbuf[0][quad * 144 + u];
    u16* wr1 = &hbuf[1][quad * 144 + u];

    // xg: ONE b64 per halfstep (gates contiguous), prefetch depth 4.
    const u16* xb = xg + (size_t)(cs & 1) * XGHALF + (size_t)g * TC * 2048 +
                    u * 16 + quad * 4;
    u64 xq0 = *(const u64*)(xb);
    u64 xq1 = *(const u64*)(xb + 2048);
    u64 xq2 = *(const u64*)(xb + 2 * 2048);
    u64 xq3 = *(const u64*)(xb + 3 * 2048);
    const u16* xp = xb + 4 * 2048;

    __syncthreads();

    auto halfstep = [&](const u16* rd, u16* wr, u64& xv) {
      // ds_reads: a0 first (feeds accA chain), a2 second (feeds accB chain)
      bf16x8 a0 = *(const bf16x8*)(rd);
      bf16x8 a2 = *(const bf16x8*)(rd + 2 * 32);
      bf16x8 a1 = *(const bf16x8*)(rd + 1 * 32);
      bf16x8 a3 = *(const bf16x8*)(rd + 3 * 32);
      // unpack this step's 4 gate pre-activations (loaded 4 halfsteps ago)
      u32 lo = (u32)xv, hi = (u32)(xv >> 32);
      float x0 = __builtin_bit_cast(float, lo << 16);
      float x1 = __builtin_bit_cast(float, lo & 0xffff0000u);
      float x2 = __builtin_bit_cast(float, hi << 16);
      float x3 = __builtin_bit_cast(float, hi & 0xffff0000u);
      // re-prefetch 4 steps ahead (stays in flight across barriers;
      // chunk-edge overshoot lands in valid ws and is discarded)
      xv = *(const u64*)xp;
      xp += 2048;
      // Two independent 2-deep MFMA chains per gate (was one 4-deep chain):
      // saves ~2 MFMA result-latencies on the serial path; merge is 1 f32 add
      // since only C reg 0 is consumed.
      const f32x4 c0 = {0.f, 0.f, 0.f, 0.f};
      f32x4 accA[4], accB[4];
#pragma unroll
      for (int j = 0; j < 4; ++j)
        accA[j] =
            __builtin_amdgcn_mfma_f32_16x16x32_bf16(a0, wf[j][0], c0, 0, 0, 0);
#pragma unroll
      for (int j = 0; j < 4; ++j)
        accB[j] =
            __builtin_amdgcn_mfma_f32_16x16x32_bf16(a2, wf[j][2], c0, 0, 0, 0);
#pragma unroll
      for (int j = 0; j < 4; ++j)
        accA[j] = __builtin_amdgcn_mfma_f32_16x16x32_bf16(a1, wf[j][1],
                                                          accA[j], 0, 0, 0);
#pragma unroll
      for (int j = 0; j < 4; ++j)
        accB[j] = __builtin_amdgcn_mfma_f32_16x16x32_bf16(a3, wf[j][3],
                                                          accB[j], 0, 0, 0);
      float zi = accA[0][0] + accB[0][0] + x0;
      float zf = accA[1][0] + accB[1][0] + x1;
      float zc = accA[2][0] + accB[2][0] + x2;
      float zo = accA[3][0] + accB[3][0] + x3;
      float ig = __builtin_amdgcn_rcpf(1.f + EXP2F(zi));
      float fg = __builtin_amdgcn_rcpf(1.f + EXP2F(zf));
      float og = __builtin_amdgcn_rcpf(1.f + EXP2F(zo));
      float gg = fmaxf(zc, 0.f);
      c1 = fg * c1 + ig * gg;
      h1 = og * fmaxf(c1, 0.f);
      *wr = bf16bits(h1);
      LDS_BARRIER();
    };

    for (int t4 = 0; t4 < TC; t4 += 4) {
      halfstep(rd0, wr1, xq0);  // t even: read buf0, write buf1
      halfstep(rd1, wr0, xq1);  // t odd:  read buf1, write buf0
      halfstep(rd0, wr1, xq2);
      halfstep(rd1, wr0, xq3);
    }

    if (cs != NCH - 1) {
      cstf[(g * 4 + quad) * 128 + u] = c1;
      hstf[(g * 4 + quad) * 128 + u] = h1;
    } else if (tid < 8) {
      // final h in hbuf[0] (t=127 wrote buf 0; barrier passed)
      int p = tid >> 1, jo = tid & 1;
      float o = bd[jo];
      for (int k = 0; k < 128; ++k)
        o += bf16f(hbuf[0][p * 144 + k]) * Wd[k * 2 + jo];
      out[(g * 4 + p) * 2 + jo] = o;
    }
  }
}

extern "C" void kernel_launch(void* const* d_in, const int* in_sizes, int n_in,
                              void* d_out, int out_size, void* d_ws, size_t ws_size,
                              hipStream_t stream) {
  const int* x = (const int*)d_in[0];
  const float* emb = (const float*)d_in[1];
  const float* Wk = (const float*)d_in[2];
  const float* Wr = (const float*)d_in[3];
  const float* bias = (const float*)d_in[4];
  const float* Wd = (const float*)d_in[5];
  const float* bd = (const float*)d_in[6];
  float* out = (float*)d_out;
  char* ws = (char*)d_ws;
  u16* xg = (u16*)(ws);
  u16* embb = (u16*)(ws + 67108864);
  u16* wkt = (u16*)(ws + 72228864);
  float* hst = (float*)(ws + 72491008);
  float* cst = (float*)(ws + 72622080);
  u16* wrt = (u16*)(ws + 72753152);

  // cs=-2: bake embb/wkt/wrt (tiny); cs=-1: xgemm(0); cs=0..6: scan(cs) ||
  // xgemm(cs+1); cs=7: scan(7) only.
  k_fused<<<521, 512, 0, stream>>>(x, emb, embb, Wk, wkt, Wr, wrt, bias, Wd,
                                   bd, xg, hst, cst, out, -2);
  for (int cs = -1; cs < NCH; ++cs) {
    int nwg = (cs + 1 < NCH) ? 576 : 64;
    k_fused<<<nwg, 512, 0, stream>>>(x, emb, embb, Wk, wkt, Wr, wrt, bias,
                                     Wd, bd, xg, hst, cst, out, cs);
  }
}